// Round 12
// baseline (1160.898 us; speedup 1.0000x reference)
//
#include <hip/hip_runtime.h>
#include <hip/hip_fp16.h>
#include <cfloat>
#include <cmath>

#define N_P 50000
#define N_W 10000
#define D_P 256
#define D_W 128
#define HID 64
#define OUTD 8
#define KH 4
#define LL 2
#define E_PP 500000
#define E_PW 150000
#define E_WP 150000
#define NTOT (N_P + N_W + N_P)
#define ETOT (E_PP + E_PW + E_WP)
#define NBP ((N_P + 63) / 64)
#define NBW ((N_W + 63) / 64)
#define NBKT ((NTOT + 255) / 256)   // 430 coarse buckets of 256 dst ids

typedef _Float16 f16x8 __attribute__((ext_vector_type(8)));
typedef float f32x4 __attribute__((ext_vector_type(4)));

__device__ inline float lrelu02(float v) { return v > 0.f ? v : 0.2f * v; }

__device__ inline f16x8 ld8h(const _Float16* p) { return *(const f16x8*)p; }
__device__ inline f16x8 ld8h(const __half* p) { return *(const f16x8*)p; }
__device__ inline f16x8 ld8h(const float* p) {
    float4 lo = *(const float4*)p;
    float4 hi = *(const float4*)(p + 4);
    f16x8 a = { (_Float16)lo.x, (_Float16)lo.y, (_Float16)lo.z, (_Float16)lo.w,
                (_Float16)hi.x, (_Float16)hi.y, (_Float16)hi.z, (_Float16)hi.w };
    return a;
}

// ---------------------------------------------------------------------------
// Shared MFMA GEMM core: C[M,64] = A[M,K] @ Bt[64,K]^T + bias (opt ELU).
// ---------------------------------------------------------------------------
template<typename AT, bool ELU>
__device__ inline void gemm64_core(const AT* __restrict__ A, const __half* __restrict__ Bt,
                                   const float* __restrict__ bias,
                                   float* __restrict__ C, __half* __restrict__ C16,
                                   int M, int K, int bid) {
    int lane = threadIdx.x & 63;
    int wv = threadIdx.x >> 6;
    int rbase = bid * 64 + wv * 16;
    int arow = min(rbase + (lane & 15), M - 1);
    int kgrp = (lane >> 4) * 8;
    const AT* Ap = A + (size_t)arow * K + kgrp;
    const _Float16* Bp = (const _Float16*)Bt + kgrp;
    int bcol = lane & 15;

    f32x4 acc0 = {0.f, 0.f, 0.f, 0.f};
    f32x4 acc1 = {0.f, 0.f, 0.f, 0.f};
    f32x4 acc2 = {0.f, 0.f, 0.f, 0.f};
    f32x4 acc3 = {0.f, 0.f, 0.f, 0.f};

#pragma unroll 4
    for (int k0 = 0; k0 < K; k0 += 32) {
        f16x8 a = ld8h(Ap + k0);
        f16x8 b0 = *(const f16x8*)(Bp + (size_t)(0 * 16 + bcol) * K + k0);
        f16x8 b1 = *(const f16x8*)(Bp + (size_t)(1 * 16 + bcol) * K + k0);
        f16x8 b2 = *(const f16x8*)(Bp + (size_t)(2 * 16 + bcol) * K + k0);
        f16x8 b3 = *(const f16x8*)(Bp + (size_t)(3 * 16 + bcol) * K + k0);
        acc0 = __builtin_amdgcn_mfma_f32_16x16x32_f16(a, b0, acc0, 0, 0, 0);
        acc1 = __builtin_amdgcn_mfma_f32_16x16x32_f16(a, b1, acc1, 0, 0, 0);
        acc2 = __builtin_amdgcn_mfma_f32_16x16x32_f16(a, b2, acc2, 0, 0, 0);
        acc3 = __builtin_amdgcn_mfma_f32_16x16x32_f16(a, b3, acc3, 0, 0, 0);
    }

    int crow = rbase + (lane >> 4) * 4;
    f32x4 accs[4] = {acc0, acc1, acc2, acc3};
#pragma unroll
    for (int t = 0; t < 4; ++t) {
        int col = t * 16 + (lane & 15);
        float bv = bias[col];
#pragma unroll
        for (int r = 0; r < 4; ++r) {
            int rr = crow + r;
            if (rr < M) {
                float v = accs[t][r] + bv;
                if (ELU) v = v > 0.f ? v : expf(v) - 1.f;
                C[(size_t)rr * 64 + col] = v;
                C16[(size_t)rr * 64 + col] = __float2half(v);
            }
        }
    }
}

// Merged input projections (protein blocks then pathway blocks).
__global__ __launch_bounds__(256) void mfma_proj2(
    const float* __restrict__ xp, const float* __restrict__ xw,
    const __half* __restrict__ wtP, const __half* __restrict__ wtW,
    const float* __restrict__ bpp, const float* __restrict__ bpw,
    float* __restrict__ hp, __half* __restrict__ hp16,
    float* __restrict__ hw, __half* __restrict__ hw16) {
    if (blockIdx.x < NBP)
        gemm64_core<float, false>(xp, wtP, bpp, hp, hp16, N_P, D_P, blockIdx.x);
    else
        gemm64_core<float, false>(xw, wtW, bpw, hw, hw16, N_W, D_W, blockIdx.x - NBP);
}

// Merged post-aggregation projections (protein K=512, pathway K=256), ELU.
__global__ __launch_bounds__(256) void mfma_postagg2(
    const __half* __restrict__ aggp, const __half* __restrict__ aggw,
    const __half* __restrict__ wtp, const __half* __restrict__ wtw,
    const float* __restrict__ bp, const float* __restrict__ bw,
    float* __restrict__ hp, __half* __restrict__ hp16,
    float* __restrict__ hw, __half* __restrict__ hw16) {
    if (blockIdx.x < NBP)
        gemm64_core<__half, true>(aggp, wtp, bp, hp, hp16, N_P, 512, blockIdx.x);
    else
        gemm64_core<__half, true>(aggw, wtw, bw, hw, hw16, N_W, 256, blockIdx.x - NBP);
}

// ---------------------------------------------------------------------------
// Message aggregation helper: accumulate alpha-weighted h over one CSR range.
// ---------------------------------------------------------------------------
__device__ inline void agg_range(int base, int len, const int* __restrict__ perm,
                                 const float4* __restrict__ alpha,
                                 const __half* __restrict__ h16,
                                 int lane, int wv,
                                 float4 (*s_al)[64], int (*s_sr)[64],
                                 float& a0, float& a1, float& a2, float& a3) {
    for (int c0 = 0; c0 < len; c0 += 64) {
        int i = c0 + lane;
        if (i < len) {
            s_sr[wv][lane] = perm[base + i];
            s_al[wv][lane] = alpha[base + i];
        }
        int cnt = min(64, len - c0);
        int j = 0;
        for (; j + 4 <= cnt; j += 4) {
            int sj0 = s_sr[wv][j], sj1 = s_sr[wv][j + 1];
            int sj2 = s_sr[wv][j + 2], sj3 = s_sr[wv][j + 3];
            float h0 = __half2float(h16[(size_t)sj0 * HID + lane]);
            float h1 = __half2float(h16[(size_t)sj1 * HID + lane]);
            float h2 = __half2float(h16[(size_t)sj2 * HID + lane]);
            float h3 = __half2float(h16[(size_t)sj3 * HID + lane]);
            float4 l0 = s_al[wv][j], l1 = s_al[wv][j + 1];
            float4 l2 = s_al[wv][j + 2], l3 = s_al[wv][j + 3];
            a0 = fmaf(l0.x, h0, a0); a1 = fmaf(l0.y, h0, a1);
            a2 = fmaf(l0.z, h0, a2); a3 = fmaf(l0.w, h0, a3);
            a0 = fmaf(l1.x, h1, a0); a1 = fmaf(l1.y, h1, a1);
            a2 = fmaf(l1.z, h1, a2); a3 = fmaf(l1.w, h1, a3);
            a0 = fmaf(l2.x, h2, a0); a1 = fmaf(l2.y, h2, a1);
            a2 = fmaf(l2.z, h2, a2); a3 = fmaf(l2.w, h2, a3);
            a0 = fmaf(l3.x, h3, a0); a1 = fmaf(l3.y, h3, a1);
            a2 = fmaf(l3.z, h3, a2); a3 = fmaf(l3.w, h3, a3);
        }
        for (; j < cnt; ++j) {
            int sj = s_sr[wv][j];
            float4 al = s_al[wv][j];
            float hv = __half2float(h16[(size_t)sj * HID + lane]);
            a0 = fmaf(al.x, hv, a0); a1 = fmaf(al.y, hv, a1);
            a2 = fmaf(al.z, hv, a2); a3 = fmaf(al.w, hv, a3);
        }
    }
}

// ---------------------------------------------------------------------------
// One dispatch for ALL message aggregation. Slots: [0,N_P) protein (pp+wp),
// [N_P, N_P+N_W) pathway (pw). alpha is UNNORMALIZED exp; normalization via
// per-(type,dst) inv vector folded into the epilogue.
// ---------------------------------------------------------------------------
__global__ __launch_bounds__(256) void gat_msg_all(
    const int* __restrict__ rowptr, const int* __restrict__ perm,
    const float4* __restrict__ alpha, const float4* __restrict__ inv,
    const __half* __restrict__ hp16, const __half* __restrict__ hw16,
    __half* __restrict__ agg_p, __half* __restrict__ agg_w) {
    __shared__ float4 s_al[4][64];
    __shared__ int s_sr[4][64];
    int lane = threadIdx.x & 63;
    int wv = threadIdx.x >> 6;
    int d = (blockIdx.x << 2) + wv;
    if (d >= N_P + N_W) return;

    if (d < N_P) {
        float a0 = 0.f, a1 = 0.f, a2 = 0.f, a3 = 0.f;
        float b0 = 0.f, b1 = 0.f, b2 = 0.f, b3 = 0.f;
        int g1 = d, g2 = N_P + N_W + d;
        int base1 = rowptr[g1], len1 = rowptr[g1 + 1] - base1;
        int base2 = rowptr[g2], len2 = rowptr[g2 + 1] - base2;
        agg_range(base1, len1, perm, alpha, hp16, lane, wv, s_al, s_sr, a0, a1, a2, a3);
        agg_range(base2, len2, perm, alpha, hw16, lane, wv, s_al, s_sr, b0, b1, b2, b3);
        float4 i1 = inv[g1], i2 = inv[g2];
        size_t ob = (size_t)d * 512 + lane;
        agg_p[ob]       = __float2half(a0 * i1.x);
        agg_p[ob + 64]  = __float2half(a1 * i1.y);
        agg_p[ob + 128] = __float2half(a2 * i1.z);
        agg_p[ob + 192] = __float2half(a3 * i1.w);
        agg_p[ob + 256] = __float2half(b0 * i2.x);
        agg_p[ob + 320] = __float2half(b1 * i2.y);
        agg_p[ob + 384] = __float2half(b2 * i2.z);
        agg_p[ob + 448] = __float2half(b3 * i2.w);
    } else {
        int d2 = d - N_P;
        int g = N_P + d2;
        float a0 = 0.f, a1 = 0.f, a2 = 0.f, a3 = 0.f;
        int base = rowptr[g], len = rowptr[g + 1] - base;
        agg_range(base, len, perm, alpha, hp16, lane, wv, s_al, s_sr, a0, a1, a2, a3);
        float4 iv = inv[g];
        size_t ob = (size_t)d2 * 256 + lane;
        agg_w[ob]       = __float2half(a0 * iv.x);
        agg_w[ob + 64]  = __float2half(a1 * iv.y);
        agg_w[ob + 128] = __float2half(a2 * iv.z);
        agg_w[ob + 192] = __float2half(a3 * iv.w);
    }
}

// Fused multi-target attention dots: oJ[n] = h[n,0:64] @ WJ[64,4]. NJ jobs.
template<int NJ>
__global__ void av_multi(const float* __restrict__ h,
                         const float* __restrict__ W0, const float* __restrict__ W1,
                         const float* __restrict__ W2, const float* __restrict__ W3,
                         float4* __restrict__ o0, float4* __restrict__ o1,
                         float4* __restrict__ o2, float4* __restrict__ o3, int M) {
    int n = blockIdx.x * blockDim.x + threadIdx.x;
    if (n >= M) return;
    const float4* h4 = (const float4*)(h + (size_t)n * HID);
    float a0[4] = {0.f, 0.f, 0.f, 0.f}, a1[4] = {0.f, 0.f, 0.f, 0.f};
    float a2[4] = {0.f, 0.f, 0.f, 0.f}, a3[4] = {0.f, 0.f, 0.f, 0.f};
#pragma unroll
    for (int k4 = 0; k4 < 16; ++k4) {
        float4 hv = h4[k4];
        float hvv[4] = {hv.x, hv.y, hv.z, hv.w};
#pragma unroll
        for (int r = 0; r < 4; ++r) {
            int f = k4 * 4 + r;
            float x = hvv[r];
#pragma unroll
            for (int c = 0; c < 4; ++c) a0[c] = fmaf(x, W0[f * 4 + c], a0[c]);
#pragma unroll
            for (int c = 0; c < 4; ++c) a1[c] = fmaf(x, W1[f * 4 + c], a1[c]);
            if (NJ > 2) {
#pragma unroll
                for (int c = 0; c < 4; ++c) a2[c] = fmaf(x, W2[f * 4 + c], a2[c]);
#pragma unroll
                for (int c = 0; c < 4; ++c) a3[c] = fmaf(x, W3[f * 4 + c], a3[c]);
            }
        }
    }
    o0[n] = make_float4(a0[0], a0[1], a0[2], a0[3]);
    o1[n] = make_float4(a1[0], a1[1], a1[2], a1[3]);
    if (NJ > 2) {
        o2[n] = make_float4(a2[0], a2[1], a2[2], a2[3]);
        o3[n] = make_float4(a3[0], a3[1], a3[2], a3[3]);
    }
}

// wv[lt][j,k] = sum_h W[lt][j, k*64+h] * att[lt][k,h].
__global__ void wv_kernel(const float* __restrict__ W, const float* __restrict__ att,
                          float* __restrict__ wv) {
    int lt = blockIdx.x;
    int j = threadIdx.x >> 2, k = threadIdx.x & 3;
    const float* Wp = W + (size_t)lt * HID * (KH * HID) + (size_t)j * (KH * HID) + k * HID;
    const float* ap = att + (size_t)lt * KH * HID + k * HID;
    float s = 0.f;
    for (int h = 0; h < HID; ++h) s += Wp[h] * ap[h];
    wv[(size_t)lt * HID * KH + j * KH + k] = s;
}

// Transposed fp16 proj weights: wtP[c][k] = Wpp[k][c] (64x256), wtW (64x128).
__global__ void build_wt_proj(const float* __restrict__ Wpp, const float* __restrict__ Wpw,
                              __half* __restrict__ wtP, __half* __restrict__ wtW) {
    int t = blockIdx.x * blockDim.x + threadIdx.x;
    if (t < 64 * 256) {
        int c = t >> 8, k = t & 255;
        wtP[t] = __float2half(Wpp[k * 64 + c]);
    } else if (t < 64 * 256 + 64 * 128) {
        int u = t - 64 * 256;
        int c = u >> 7, k = u & 127;
        wtW[u] = __float2half(Wpw[k * 64 + c]);
    }
}

// Transposed fp16 combined weights for BOTH layers; head-mean (0.25) and
// hetero-mean (0.5) folded here ONLY (alpha normalization lives in msg inv).
__global__ void build_wcomb16(const float* __restrict__ Wsrc, const float* __restrict__ cbias,
                              __half* __restrict__ wtp, float* __restrict__ bp,
                              __half* __restrict__ wtw, float* __restrict__ bw) {
    int t = blockIdx.x * blockDim.x + threadIdx.x;
    const int P = LL * 64 * 512;
    if (t < P) {
        int l = t / (64 * 512);
        int rem = t % (64 * 512);
        int h = rem >> 9, r = rem & 511;
        int part = r >> 8, k = (r & 255) >> 6, j = r & 63;
        int type = (part == 0) ? 0 : 2;
        wtp[t] = __float2half(Wsrc[(((size_t)l * 3 + type) * 64 + j) * 256 + k * 64 + h] * 0.125f);
    } else if (t < P + LL * 64 * 256) {
        int u = t - P;
        int l = u / (64 * 256);
        int rem = u % (64 * 256);
        int h = rem >> 8, r = rem & 255;
        int k = r >> 6, j = r & 63;
        wtw[u] = __float2half(Wsrc[(((size_t)l * 3 + 1) * 64 + j) * 256 + k * 64 + h] * 0.25f);
    }
    if (t < LL * 64) {
        int l = t >> 6, c = t & 63;
        bp[t] = 0.5f * (cbias[(l * 3 + 0) * 64 + c] + cbias[(l * 3 + 2) * 64 + c]);
        bw[t] = cbias[(l * 3 + 1) * 64 + c];
    }
}

// ---------------- bucket-based CSR build ----------------
// bucket = global_dst >> 8 (430 buckets). Atomics touch only 430 hot lines.
__global__ void count_bucket(const int* __restrict__ ei_pp, const int* __restrict__ ei_pw,
                             const int* __restrict__ ei_wp, int* __restrict__ bcnt) {
    int e = blockIdx.x * blockDim.x + threadIdx.x;
    if (e >= ETOT) return;
    const int* ei; int eo, no, E;
    if (e < E_PP) { ei = ei_pp; eo = 0; no = 0; E = E_PP; }
    else if (e < E_PP + E_PW) { ei = ei_pw; eo = E_PP; no = N_P; E = E_PW; }
    else { ei = ei_wp; eo = E_PP + E_PW; no = N_P + N_W; E = E_WP; }
    int el = e - eo;
    int g = no + ei[E + el];
    atomicAdd(&bcnt[g >> 8], 1);
}

// Single block: exclusive scan of bcnt[0..NBKT) -> bbase (and copy to bwoff);
// bbase[NBKT] = total.
__global__ __launch_bounds__(512) void scan_buckets(const int* __restrict__ bcnt,
                                                    int* __restrict__ bbase,
                                                    int* __restrict__ bwoff) {
    __shared__ int wsum[8], wexc[8];
    int tid = threadIdx.x, lane = tid & 63, wv = tid >> 6;
    int v = (tid < NBKT) ? bcnt[tid] : 0;
    int x = v;
#pragma unroll
    for (int off = 1; off < 64; off <<= 1) {
        int y = __shfl_up(x, off, 64);
        if (lane >= off) x += y;
    }
    if (lane == 63) wsum[wv] = x;
    __syncthreads();
    if (wv == 0 && lane < 8) {
        int s = wsum[lane];
        int xx = s;
#pragma unroll
        for (int off = 1; off < 8; off <<= 1) {
            int y = __shfl_up(xx, off, 8);
            if (lane >= off) xx += y;
        }
        wexc[lane] = xx - s;
    }
    __syncthreads();
    int excl = x - v + wexc[wv];
    if (tid < NBKT) { bbase[tid] = excl; bwoff[tid] = excl; }
    if (tid == NBKT - 1) bbase[NBKT] = excl + v;
}

// Scatter edges into bucket-contiguous temp as (g_dst, src_local) pairs.
__global__ void scatter_bucket(const int* __restrict__ ei_pp, const int* __restrict__ ei_pw,
                               const int* __restrict__ ei_wp, int* __restrict__ bwoff,
                               int2* __restrict__ temp) {
    int e = blockIdx.x * blockDim.x + threadIdx.x;
    if (e >= ETOT) return;
    const int* ei; int eo, no, E;
    if (e < E_PP) { ei = ei_pp; eo = 0; no = 0; E = E_PP; }
    else if (e < E_PP + E_PW) { ei = ei_pw; eo = E_PP; no = N_P; E = E_PW; }
    else { ei = ei_wp; eo = E_PP + E_PW; no = N_P + N_W; E = E_WP; }
    int el = e - eo;
    int g = no + ei[E + el];
    int p = atomicAdd(&bwoff[g >> 8], 1);
    temp[p] = make_int2(g, ei[el]);
}

// Per-bucket counting sort: 256-bin LDS histogram + scan -> rowptr + perm.
// No global atomics. Block b handles dst ids [b*256, (b+1)*256).
__global__ __launch_bounds__(256) void bucket_sort(const int2* __restrict__ temp,
                                                   const int* __restrict__ bbase,
                                                   int* __restrict__ rowptr,
                                                   int* __restrict__ perm) {
    __shared__ int hist[256];
    __shared__ int offs[256];
    __shared__ int wtot[4];
    int b = blockIdx.x;
    int tid = threadIdx.x;
    int bstart = bbase[b], bend = bbase[b + 1];
    hist[tid] = 0;
    __syncthreads();
    for (int i = bstart + tid; i < bend; i += 256)
        atomicAdd(&hist[temp[i].x & 255], 1);
    __syncthreads();
    // exclusive scan of hist[256] with 4 waves
    int v = hist[tid];
    int lane = tid & 63, wv = tid >> 6;
    int x = v;
#pragma unroll
    for (int off = 1; off < 64; off <<= 1) {
        int y = __shfl_up(x, off, 64);
        if (lane >= off) x += y;
    }
    if (lane == 63) wtot[wv] = x;
    __syncthreads();
    int add = 0;
#pragma unroll
    for (int k = 0; k < 4; ++k) add += (k < wv) ? wtot[k] : 0;
    int excl = x - v + add;
    int d_global = b * 256 + tid;
    if (d_global <= NTOT) rowptr[d_global] = bstart + excl;
    offs[tid] = excl;
    __syncthreads();
    for (int i = bstart + tid; i < bend; i += 256) {
        int2 t = temp[i];
        int r = atomicAdd(&offs[t.x & 255], 1);
        perm[bstart + r] = t.y;
    }
}

// ---------------------------------------------------------------------------
// Per-edge unnormalized exp + per-dst inverse-sum. One THREAD per (type,dst).
// ---------------------------------------------------------------------------
__global__ void gat_stats3(const int* __restrict__ rowptr, const int* __restrict__ perm,
                           const float4* __restrict__ a_pp_s, const float4* __restrict__ a_pp_d,
                           const float4* __restrict__ a_pw_s, const float4* __restrict__ a_pw_d,
                           const float4* __restrict__ a_wp_s, const float4* __restrict__ a_wp_d,
                           float4* __restrict__ alpha, float4* __restrict__ inv) {
    int g = blockIdx.x * blockDim.x + threadIdx.x;
    if (g >= NTOT) return;
    const float4 *as, *ad; int d;
    if (g < N_P) { as = a_pp_s; ad = a_pp_d; d = g; }
    else if (g < N_P + N_W) { as = a_pw_s; ad = a_pw_d; d = g - N_P; }
    else { as = a_wp_s; ad = a_wp_d; d = g - (N_P + N_W); }
    int base = rowptr[g], end = rowptr[g + 1];
    float4 adv = ad[d];
    float4 sm = make_float4(0.f, 0.f, 0.f, 0.f);
    for (int i = base; i < end; ++i) {
        float4 asv = as[perm[i]];
        float4 t;
        t.x = __expf(lrelu02(asv.x + adv.x));
        t.y = __expf(lrelu02(asv.y + adv.y));
        t.z = __expf(lrelu02(asv.z + adv.z));
        t.w = __expf(lrelu02(asv.w + adv.w));
        alpha[i] = t;
        sm.x += t.x; sm.y += t.y; sm.z += t.z; sm.w += t.w;
    }
    float4 iv;
    int len = end - base;
    iv.x = len ? 1.f / sm.x : 0.f;
    iv.y = len ? 1.f / sm.y : 0.f;
    iv.z = len ? 1.f / sm.z : 0.f;
    iv.w = len ? 1.f / sm.w : 0.f;
    inv[g] = iv;
}

// Final projections for both node types in one launch.
__global__ void post_out(const float* __restrict__ h_p, const float* __restrict__ h_w,
                         const float* __restrict__ Wp, const float* __restrict__ bpv,
                         const float* __restrict__ Ww, const float* __restrict__ bwv,
                         float* __restrict__ out) {
    int n = blockIdx.x * blockDim.x + threadIdx.x;
    if (n >= N_P + N_W) return;
    const float *h, *W, *bb; float* o;
    if (n < N_P) { h = h_p + (size_t)n * HID; W = Wp; bb = bpv; o = out + (size_t)n * OUTD; }
    else { int m = n - N_P; h = h_w + (size_t)m * HID; W = Ww; bb = bwv; o = out + (size_t)N_P * OUTD + (size_t)m * OUTD; }
    const float4* h4 = (const float4*)h;
    float acc[OUTD];
#pragma unroll
    for (int c = 0; c < OUTD; ++c) acc[c] = bb[c];
#pragma unroll
    for (int k4 = 0; k4 < HID / 4; ++k4) {
        float4 hv = h4[k4];
#pragma unroll
        for (int c = 0; c < OUTD; ++c) {
            acc[c] = fmaf(hv.x, W[(k4 * 4 + 0) * OUTD + c], acc[c]);
            acc[c] = fmaf(hv.y, W[(k4 * 4 + 1) * OUTD + c], acc[c]);
            acc[c] = fmaf(hv.z, W[(k4 * 4 + 2) * OUTD + c], acc[c]);
            acc[c] = fmaf(hv.w, W[(k4 * 4 + 3) * OUTD + c], acc[c]);
        }
    }
#pragma unroll
    for (int c4 = 0; c4 < OUTD / 4; ++c4)
        *(float4*)&o[c4 * 4] = make_float4(acc[c4 * 4], acc[c4 * 4 + 1], acc[c4 * 4 + 2], acc[c4 * 4 + 3]);
}

extern "C" void kernel_launch(void* const* d_in, const int* in_sizes, int n_in,
                              void* d_out, int out_size, void* d_ws, size_t ws_size,
                              hipStream_t stream) {
    const float* x_p    = (const float*)d_in[0];
    const float* x_w    = (const float*)d_in[1];
    const float* Wpp    = (const float*)d_in[2];
    const float* bpp    = (const float*)d_in[3];
    const float* Wpw    = (const float*)d_in[4];
    const float* bpw    = (const float*)d_in[5];
    const float* Wsrc   = (const float*)d_in[6];
    const float* Wdst   = (const float*)d_in[7];
    const float* Asrc   = (const float*)d_in[8];
    const float* Adst   = (const float*)d_in[9];
    const float* cbias  = (const float*)d_in[10];
    const float* Wpostp = (const float*)d_in[11];
    const float* bpostp = (const float*)d_in[12];
    const float* Wpostw = (const float*)d_in[13];
    const float* bpostw = (const float*)d_in[14];
    const int*   ei_pp  = (const int*)d_in[15];
    const int*   ei_pw  = (const int*)d_in[16];
    const int*   ei_wp  = (const int*)d_in[17];

    char* base = (char*)d_ws;
    size_t off = 0;
    auto alloc = [&](size_t bytes) -> void* {
        void* p = base + off;
        off = (off + bytes + 15) & ~(size_t)15;
        return p;
    };

    float*  hp[2];  hp[0]  = (float*)alloc((size_t)N_P * HID * 4);
                    hp[1]  = (float*)alloc((size_t)N_P * HID * 4);
    float*  hw[2];  hw[0]  = (float*)alloc((size_t)N_W * HID * 4);
                    hw[1]  = (float*)alloc((size_t)N_W * HID * 4);
    __half* hp16[2]; hp16[0] = (__half*)alloc((size_t)N_P * HID * 2);
                     hp16[1] = (__half*)alloc((size_t)N_P * HID * 2);
    __half* hw16[2]; hw16[0] = (__half*)alloc((size_t)N_W * HID * 2);
                     hw16[1] = (__half*)alloc((size_t)N_W * HID * 2);
    __half* agg_p  = (__half*)alloc((size_t)N_P * 512 * 2);
    __half* agg_w  = (__half*)alloc((size_t)N_W * 256 * 2);
    float*  wv_s   = (float*)alloc((size_t)LL * 3 * HID * KH * 4);
    float*  wv_d   = (float*)alloc((size_t)LL * 3 * HID * KH * 4);
    __half* wtP    = (__half*)alloc(64 * 256 * 2);
    __half* wtW    = (__half*)alloc(64 * 128 * 2);
    __half* wtp    = (__half*)alloc((size_t)LL * 64 * 512 * 2);
    __half* wtw    = (__half*)alloc((size_t)LL * 64 * 256 * 2);
    float*  bp     = (float*)alloc(LL * 64 * 4);
    float*  bw     = (float*)alloc(LL * 64 * 4);
    float*  a_pp_s = (float*)alloc((size_t)N_P * KH * 4);
    float*  a_pp_d = (float*)alloc((size_t)N_P * KH * 4);
    float*  a_pw_s = (float*)alloc((size_t)N_P * KH * 4);
    float*  a_pw_d = (float*)alloc((size_t)N_W * KH * 4);
    float*  a_wp_s = (float*)alloc((size_t)N_W * KH * 4);
    float*  a_wp_d = (float*)alloc((size_t)N_P * KH * 4);
    float*  alpha  = (float*)alloc((size_t)ETOT * KH * 4);
    float*  inv    = (float*)alloc((size_t)NTOT * KH * 4);
    int*    rowptr = (int*)alloc(((size_t)NTOT + 1) * 4);
    int*    perm   = (int*)alloc((size_t)ETOT * 4);
    int*    bcnt   = (int*)alloc((NBKT + 1) * 4);
    int*    bbase  = (int*)alloc((NBKT + 1) * 4);
    int*    bwoff  = (int*)alloc((NBKT + 1) * 4);
    int2*   temp   = (int2*)alloc((size_t)ETOT * 8);

    auto cdiv = [](long long a, long long b) { return (int)((a + b - 1) / b); };

    // weight preprocessing
    wv_kernel<<<LL * 3, 256, 0, stream>>>(Wsrc, Asrc, wv_s);
    wv_kernel<<<LL * 3, 256, 0, stream>>>(Wdst, Adst, wv_d);
    build_wt_proj<<<cdiv(64 * 256 + 64 * 128, 256), 256, 0, stream>>>(Wpp, Wpw, wtP, wtW);
    build_wcomb16<<<cdiv(LL * 64 * (512 + 256), 256), 256, 0, stream>>>(Wsrc, cbias, wtp, bp, wtw, bw);

    // bucket-based CSR build
    (void)hipMemsetAsync(bcnt, 0, (NBKT + 1) * 4, stream);
    count_bucket<<<cdiv(ETOT, 256), 256, 0, stream>>>(ei_pp, ei_pw, ei_wp, bcnt);
    scan_buckets<<<1, 512, 0, stream>>>(bcnt, bbase, bwoff);
    scatter_bucket<<<cdiv(ETOT, 256), 256, 0, stream>>>(ei_pp, ei_pw, ei_wp, bwoff, temp);
    bucket_sort<<<NBKT, 256, 0, stream>>>(temp, bbase, rowptr, perm);

    // input projections (both node types, one dispatch)
    mfma_proj2<<<NBP + NBW, 256, 0, stream>>>(x_p, x_w, wtP, wtW, bpp, bpw,
                                              hp[0], hp16[0], hw[0], hw16[0]);

    int cur = 0;
    for (int l = 0; l < LL; ++l) {
        int lt0 = l * 3 + 0, lt1 = l * 3 + 1, lt2 = l * 3 + 2;
        av_multi<4><<<cdiv(N_P, 256), 256, 0, stream>>>(
            hp[cur], wv_s + (size_t)lt0 * 256, wv_d + (size_t)lt0 * 256,
            wv_s + (size_t)lt1 * 256, wv_d + (size_t)lt2 * 256,
            (float4*)a_pp_s, (float4*)a_pp_d, (float4*)a_pw_s, (float4*)a_wp_d, N_P);
        av_multi<2><<<cdiv(N_W, 256), 256, 0, stream>>>(
            hw[cur], wv_d + (size_t)lt1 * 256, wv_s + (size_t)lt2 * 256, nullptr, nullptr,
            (float4*)a_pw_d, (float4*)a_wp_s, nullptr, nullptr, N_W);

        gat_stats3<<<cdiv(NTOT, 256), 256, 0, stream>>>(
            rowptr, perm,
            (const float4*)a_pp_s, (const float4*)a_pp_d,
            (const float4*)a_pw_s, (const float4*)a_pw_d,
            (const float4*)a_wp_s, (const float4*)a_wp_d,
            (float4*)alpha, (float4*)inv);

        gat_msg_all<<<cdiv(N_P + N_W, 4), 256, 0, stream>>>(
            rowptr, perm, (const float4*)alpha, (const float4*)inv,
            hp16[cur], hw16[cur], agg_p, agg_w);

        mfma_postagg2<<<NBP + NBW, 256, 0, stream>>>(
            agg_p, agg_w, wtp + (size_t)l * 64 * 512, wtw + (size_t)l * 64 * 256,
            bp + l * 64, bw + l * 64,
            hp[cur ^ 1], hp16[cur ^ 1], hw[cur ^ 1], hw16[cur ^ 1]);
        cur ^= 1;
    }

    post_out<<<cdiv(N_P + N_W, 256), 256, 0, stream>>>(
        hp[cur], hw[cur], Wpostp, bpostp, Wpostw, bpostw, (float*)d_out);
}

// Round 13
// 373.174 us; speedup vs baseline: 3.1109x; 3.1109x over previous
//
#include <hip/hip_runtime.h>
#include <hip/hip_fp16.h>
#include <cfloat>
#include <cmath>

#define N_P 50000
#define N_W 10000
#define D_P 256
#define D_W 128
#define HID 64
#define OUTD 8
#define KH 4
#define LL 2
#define E_PP 500000
#define E_PW 150000
#define E_WP 150000
#define NTOT (N_P + N_W + N_P)
#define ETOT (E_PP + E_PW + E_WP)
#define NBP ((N_P + 63) / 64)
#define NBW ((N_W + 63) / 64)

typedef _Float16 f16x8 __attribute__((ext_vector_type(8)));
typedef float f32x4 __attribute__((ext_vector_type(4)));

__device__ inline float lrelu02(float v) { return v > 0.f ? v : 0.2f * v; }

__device__ inline f16x8 ld8h(const _Float16* p) { return *(const f16x8*)p; }
__device__ inline f16x8 ld8h(const __half* p) { return *(const f16x8*)p; }
__device__ inline f16x8 ld8h(const float* p) {
    float4 lo = *(const float4*)p;
    float4 hi = *(const float4*)(p + 4);
    f16x8 a = { (_Float16)lo.x, (_Float16)lo.y, (_Float16)lo.z, (_Float16)lo.w,
                (_Float16)hi.x, (_Float16)hi.y, (_Float16)hi.z, (_Float16)hi.w };
    return a;
}

// ---------------------------------------------------------------------------
// Shared MFMA GEMM core: C[M,64] = A[M,K] @ Bt[64,K]^T + bias (opt ELU).
// ---------------------------------------------------------------------------
template<typename AT, bool ELU>
__device__ inline void gemm64_core(const AT* __restrict__ A, const __half* __restrict__ Bt,
                                   const float* __restrict__ bias,
                                   float* __restrict__ C, __half* __restrict__ C16,
                                   int M, int K, int bid) {
    int lane = threadIdx.x & 63;
    int wv = threadIdx.x >> 6;
    int rbase = bid * 64 + wv * 16;
    int arow = min(rbase + (lane & 15), M - 1);
    int kgrp = (lane >> 4) * 8;
    const AT* Ap = A + (size_t)arow * K + kgrp;
    const _Float16* Bp = (const _Float16*)Bt + kgrp;
    int bcol = lane & 15;

    f32x4 acc0 = {0.f, 0.f, 0.f, 0.f};
    f32x4 acc1 = {0.f, 0.f, 0.f, 0.f};
    f32x4 acc2 = {0.f, 0.f, 0.f, 0.f};
    f32x4 acc3 = {0.f, 0.f, 0.f, 0.f};

#pragma unroll 4
    for (int k0 = 0; k0 < K; k0 += 32) {
        f16x8 a = ld8h(Ap + k0);
        f16x8 b0 = *(const f16x8*)(Bp + (size_t)(0 * 16 + bcol) * K + k0);
        f16x8 b1 = *(const f16x8*)(Bp + (size_t)(1 * 16 + bcol) * K + k0);
        f16x8 b2 = *(const f16x8*)(Bp + (size_t)(2 * 16 + bcol) * K + k0);
        f16x8 b3 = *(const f16x8*)(Bp + (size_t)(3 * 16 + bcol) * K + k0);
        acc0 = __builtin_amdgcn_mfma_f32_16x16x32_f16(a, b0, acc0, 0, 0, 0);
        acc1 = __builtin_amdgcn_mfma_f32_16x16x32_f16(a, b1, acc1, 0, 0, 0);
        acc2 = __builtin_amdgcn_mfma_f32_16x16x32_f16(a, b2, acc2, 0, 0, 0);
        acc3 = __builtin_amdgcn_mfma_f32_16x16x32_f16(a, b3, acc3, 0, 0, 0);
    }

    int crow = rbase + (lane >> 4) * 4;
    f32x4 accs[4] = {acc0, acc1, acc2, acc3};
#pragma unroll
    for (int t = 0; t < 4; ++t) {
        int col = t * 16 + (lane & 15);
        float bv = bias[col];
#pragma unroll
        for (int r = 0; r < 4; ++r) {
            int rr = crow + r;
            if (rr < M) {
                float v = accs[t][r] + bv;
                if (ELU) v = v > 0.f ? v : expf(v) - 1.f;
                C[(size_t)rr * 64 + col] = v;
                C16[(size_t)rr * 64 + col] = __float2half(v);
            }
        }
    }
}

// Merged input projections (protein blocks then pathway blocks).
__global__ __launch_bounds__(256) void mfma_proj2(
    const float* __restrict__ xp, const float* __restrict__ xw,
    const __half* __restrict__ wtP, const __half* __restrict__ wtW,
    const float* __restrict__ bpp, const float* __restrict__ bpw,
    float* __restrict__ hp, __half* __restrict__ hp16,
    float* __restrict__ hw, __half* __restrict__ hw16) {
    if (blockIdx.x < NBP)
        gemm64_core<float, false>(xp, wtP, bpp, hp, hp16, N_P, D_P, blockIdx.x);
    else
        gemm64_core<float, false>(xw, wtW, bpw, hw, hw16, N_W, D_W, blockIdx.x - NBP);
}

// Merged post-aggregation projections (protein K=512, pathway K=256), ELU.
__global__ __launch_bounds__(256) void mfma_postagg2(
    const __half* __restrict__ aggp, const __half* __restrict__ aggw,
    const __half* __restrict__ wtp, const __half* __restrict__ wtw,
    const float* __restrict__ bp, const float* __restrict__ bw,
    float* __restrict__ hp, __half* __restrict__ hp16,
    float* __restrict__ hw, __half* __restrict__ hw16) {
    if (blockIdx.x < NBP)
        gemm64_core<__half, true>(aggp, wtp, bp, hp, hp16, N_P, 512, blockIdx.x);
    else
        gemm64_core<__half, true>(aggw, wtw, bw, hw, hw16, N_W, 256, blockIdx.x - NBP);
}

// ---------------------------------------------------------------------------
// Message aggregation helper: accumulate alpha-weighted h over one CSR range.
// ---------------------------------------------------------------------------
__device__ inline void agg_range(int base, int len, const int* __restrict__ perm,
                                 const float4* __restrict__ alpha,
                                 const __half* __restrict__ h16,
                                 int lane, int wv,
                                 float4 (*s_al)[64], int (*s_sr)[64],
                                 float& a0, float& a1, float& a2, float& a3) {
    for (int c0 = 0; c0 < len; c0 += 64) {
        int i = c0 + lane;
        if (i < len) {
            s_sr[wv][lane] = perm[base + i];
            s_al[wv][lane] = alpha[base + i];
        }
        int cnt = min(64, len - c0);
        int j = 0;
        for (; j + 4 <= cnt; j += 4) {
            int sj0 = s_sr[wv][j], sj1 = s_sr[wv][j + 1];
            int sj2 = s_sr[wv][j + 2], sj3 = s_sr[wv][j + 3];
            float h0 = __half2float(h16[(size_t)sj0 * HID + lane]);
            float h1 = __half2float(h16[(size_t)sj1 * HID + lane]);
            float h2 = __half2float(h16[(size_t)sj2 * HID + lane]);
            float h3 = __half2float(h16[(size_t)sj3 * HID + lane]);
            float4 l0 = s_al[wv][j], l1 = s_al[wv][j + 1];
            float4 l2 = s_al[wv][j + 2], l3 = s_al[wv][j + 3];
            a0 = fmaf(l0.x, h0, a0); a1 = fmaf(l0.y, h0, a1);
            a2 = fmaf(l0.z, h0, a2); a3 = fmaf(l0.w, h0, a3);
            a0 = fmaf(l1.x, h1, a0); a1 = fmaf(l1.y, h1, a1);
            a2 = fmaf(l1.z, h1, a2); a3 = fmaf(l1.w, h1, a3);
            a0 = fmaf(l2.x, h2, a0); a1 = fmaf(l2.y, h2, a1);
            a2 = fmaf(l2.z, h2, a2); a3 = fmaf(l2.w, h2, a3);
            a0 = fmaf(l3.x, h3, a0); a1 = fmaf(l3.y, h3, a1);
            a2 = fmaf(l3.z, h3, a2); a3 = fmaf(l3.w, h3, a3);
        }
        for (; j < cnt; ++j) {
            int sj = s_sr[wv][j];
            float4 al = s_al[wv][j];
            float hv = __half2float(h16[(size_t)sj * HID + lane]);
            a0 = fmaf(al.x, hv, a0); a1 = fmaf(al.y, hv, a1);
            a2 = fmaf(al.z, hv, a2); a3 = fmaf(al.w, hv, a3);
        }
    }
}

// ---------------------------------------------------------------------------
// One dispatch for ALL message aggregation. Slots: [0,N_P) protein (pp+wp),
// [N_P, N_P+N_W) pathway (pw). alpha is UNNORMALIZED exp; normalization via
// per-(type,dst) inv vector folded into the epilogue.
// ---------------------------------------------------------------------------
__global__ __launch_bounds__(256) void gat_msg_all(
    const int* __restrict__ rowptr, const int* __restrict__ perm,
    const float4* __restrict__ alpha, const float4* __restrict__ inv,
    const __half* __restrict__ hp16, const __half* __restrict__ hw16,
    __half* __restrict__ agg_p, __half* __restrict__ agg_w) {
    __shared__ float4 s_al[4][64];
    __shared__ int s_sr[4][64];
    int lane = threadIdx.x & 63;
    int wv = threadIdx.x >> 6;
    int d = (blockIdx.x << 2) + wv;
    if (d >= N_P + N_W) return;

    if (d < N_P) {
        float a0 = 0.f, a1 = 0.f, a2 = 0.f, a3 = 0.f;
        float b0 = 0.f, b1 = 0.f, b2 = 0.f, b3 = 0.f;
        int g1 = d, g2 = N_P + N_W + d;
        int base1 = rowptr[g1], len1 = rowptr[g1 + 1] - base1;
        int base2 = rowptr[g2], len2 = rowptr[g2 + 1] - base2;
        agg_range(base1, len1, perm, alpha, hp16, lane, wv, s_al, s_sr, a0, a1, a2, a3);
        agg_range(base2, len2, perm, alpha, hw16, lane, wv, s_al, s_sr, b0, b1, b2, b3);
        float4 i1 = inv[g1], i2 = inv[g2];
        size_t ob = (size_t)d * 512 + lane;
        agg_p[ob]       = __float2half(a0 * i1.x);
        agg_p[ob + 64]  = __float2half(a1 * i1.y);
        agg_p[ob + 128] = __float2half(a2 * i1.z);
        agg_p[ob + 192] = __float2half(a3 * i1.w);
        agg_p[ob + 256] = __float2half(b0 * i2.x);
        agg_p[ob + 320] = __float2half(b1 * i2.y);
        agg_p[ob + 384] = __float2half(b2 * i2.z);
        agg_p[ob + 448] = __float2half(b3 * i2.w);
    } else {
        int d2 = d - N_P;
        int g = N_P + d2;
        float a0 = 0.f, a1 = 0.f, a2 = 0.f, a3 = 0.f;
        int base = rowptr[g], len = rowptr[g + 1] - base;
        agg_range(base, len, perm, alpha, hp16, lane, wv, s_al, s_sr, a0, a1, a2, a3);
        float4 iv = inv[g];
        size_t ob = (size_t)d2 * 256 + lane;
        agg_w[ob]       = __float2half(a0 * iv.x);
        agg_w[ob + 64]  = __float2half(a1 * iv.y);
        agg_w[ob + 128] = __float2half(a2 * iv.z);
        agg_w[ob + 192] = __float2half(a3 * iv.w);
    }
}

// Fused multi-target attention dots: oJ[n] = h[n,0:64] @ WJ[64,4]. NJ jobs.
template<int NJ>
__global__ void av_multi(const float* __restrict__ h,
                         const float* __restrict__ W0, const float* __restrict__ W1,
                         const float* __restrict__ W2, const float* __restrict__ W3,
                         float4* __restrict__ o0, float4* __restrict__ o1,
                         float4* __restrict__ o2, float4* __restrict__ o3, int M) {
    int n = blockIdx.x * blockDim.x + threadIdx.x;
    if (n >= M) return;
    const float4* h4 = (const float4*)(h + (size_t)n * HID);
    float a0[4] = {0.f, 0.f, 0.f, 0.f}, a1[4] = {0.f, 0.f, 0.f, 0.f};
    float a2[4] = {0.f, 0.f, 0.f, 0.f}, a3[4] = {0.f, 0.f, 0.f, 0.f};
#pragma unroll
    for (int k4 = 0; k4 < 16; ++k4) {
        float4 hv = h4[k4];
        float hvv[4] = {hv.x, hv.y, hv.z, hv.w};
#pragma unroll
        for (int r = 0; r < 4; ++r) {
            int f = k4 * 4 + r;
            float x = hvv[r];
#pragma unroll
            for (int c = 0; c < 4; ++c) a0[c] = fmaf(x, W0[f * 4 + c], a0[c]);
#pragma unroll
            for (int c = 0; c < 4; ++c) a1[c] = fmaf(x, W1[f * 4 + c], a1[c]);
            if (NJ > 2) {
#pragma unroll
                for (int c = 0; c < 4; ++c) a2[c] = fmaf(x, W2[f * 4 + c], a2[c]);
#pragma unroll
                for (int c = 0; c < 4; ++c) a3[c] = fmaf(x, W3[f * 4 + c], a3[c]);
            }
        }
    }
    o0[n] = make_float4(a0[0], a0[1], a0[2], a0[3]);
    o1[n] = make_float4(a1[0], a1[1], a1[2], a1[3]);
    if (NJ > 2) {
        o2[n] = make_float4(a2[0], a2[1], a2[2], a2[3]);
        o3[n] = make_float4(a3[0], a3[1], a3[2], a3[3]);
    }
}

// wv[lt][j,k] = sum_h W[lt][j, k*64+h] * att[lt][k,h].
__global__ void wv_kernel(const float* __restrict__ W, const float* __restrict__ att,
                          float* __restrict__ wv) {
    int lt = blockIdx.x;
    int j = threadIdx.x >> 2, k = threadIdx.x & 3;
    const float* Wp = W + (size_t)lt * HID * (KH * HID) + (size_t)j * (KH * HID) + k * HID;
    const float* ap = att + (size_t)lt * KH * HID + k * HID;
    float s = 0.f;
    for (int h = 0; h < HID; ++h) s += Wp[h] * ap[h];
    wv[(size_t)lt * HID * KH + j * KH + k] = s;
}

// Transposed fp16 proj weights: wtP[c][k] = Wpp[k][c] (64x256), wtW (64x128).
__global__ void build_wt_proj(const float* __restrict__ Wpp, const float* __restrict__ Wpw,
                              __half* __restrict__ wtP, __half* __restrict__ wtW) {
    int t = blockIdx.x * blockDim.x + threadIdx.x;
    if (t < 64 * 256) {
        int c = t >> 8, k = t & 255;
        wtP[t] = __float2half(Wpp[k * 64 + c]);
    } else if (t < 64 * 256 + 64 * 128) {
        int u = t - 64 * 256;
        int c = u >> 7, k = u & 127;
        wtW[u] = __float2half(Wpw[k * 64 + c]);
    }
}

// Transposed fp16 combined weights for BOTH layers; head-mean (0.25) and
// hetero-mean (0.5) folded here ONLY (alpha normalization lives in msg inv).
__global__ void build_wcomb16(const float* __restrict__ Wsrc, const float* __restrict__ cbias,
                              __half* __restrict__ wtp, float* __restrict__ bp,
                              __half* __restrict__ wtw, float* __restrict__ bw) {
    int t = blockIdx.x * blockDim.x + threadIdx.x;
    const int P = LL * 64 * 512;
    if (t < P) {
        int l = t / (64 * 512);
        int rem = t % (64 * 512);
        int h = rem >> 9, r = rem & 511;
        int part = r >> 8, k = (r & 255) >> 6, j = r & 63;
        int type = (part == 0) ? 0 : 2;
        wtp[t] = __float2half(Wsrc[(((size_t)l * 3 + type) * 64 + j) * 256 + k * 64 + h] * 0.125f);
    } else if (t < P + LL * 64 * 256) {
        int u = t - P;
        int l = u / (64 * 256);
        int rem = u % (64 * 256);
        int h = rem >> 8, r = rem & 255;
        int k = r >> 6, j = r & 63;
        wtw[u] = __float2half(Wsrc[(((size_t)l * 3 + 1) * 64 + j) * 256 + k * 64 + h] * 0.25f);
    }
    if (t < LL * 64) {
        int l = t >> 6, c = t & 63;
        bp[t] = 0.5f * (cbias[(l * 3 + 0) * 64 + c] + cbias[(l * 3 + 2) * 64 + c]);
        bw[t] = cbias[(l * 3 + 1) * 64 + c];
    }
}

// ---------------- concatenated CSR build (round-11 proven version) ----------
__global__ void count3_kernel(const int* __restrict__ ei_pp, const int* __restrict__ ei_pw,
                              const int* __restrict__ ei_wp, int* __restrict__ cnt) {
    int e = blockIdx.x * blockDim.x + threadIdx.x;
    if (e >= ETOT) return;
    const int* ei; int eo, no, E;
    if (e < E_PP) { ei = ei_pp; eo = 0; no = 0; E = E_PP; }
    else if (e < E_PP + E_PW) { ei = ei_pw; eo = E_PP; no = N_P; E = E_PW; }
    else { ei = ei_wp; eo = E_PP + E_PW; no = N_P + N_W; E = E_WP; }
    int el = e - eo;
    atomicAdd(&cnt[no + ei[E + el]], 1);
}

__global__ __launch_bounds__(1024) void block_sum_kernel(const int* __restrict__ cnt,
                                                         int* __restrict__ bsum, int n) {
    __shared__ int wsum[16];
    int tid = threadIdx.x, lane = tid & 63, wv = tid >> 6;
    int i = blockIdx.x * 1024 + tid;
    int v = (i < n) ? cnt[i] : 0;
#pragma unroll
    for (int off = 32; off > 0; off >>= 1) v += __shfl_xor(v, off, 64);
    if (lane == 0) wsum[wv] = v;
    __syncthreads();
    if (tid == 0) {
        int t = 0;
#pragma unroll
        for (int k = 0; k < 16; ++k) t += wsum[k];
        bsum[blockIdx.x] = t;
    }
}

__global__ __launch_bounds__(1024) void scan_bsums_kernel(int* __restrict__ bsum, int nb) {
    __shared__ int wsum[16], wexc[16];
    int tid = threadIdx.x, lane = tid & 63, wv = tid >> 6;
    int v = (tid < nb) ? bsum[tid] : 0;
    int x = v;
#pragma unroll
    for (int off = 1; off < 64; off <<= 1) {
        int y = __shfl_up(x, off, 64);
        if (lane >= off) x += y;
    }
    if (lane == 63) wsum[wv] = x;
    __syncthreads();
    if (wv == 0 && lane < 16) {
        int s = wsum[lane];
        int xx = s;
#pragma unroll
        for (int off = 1; off < 16; off <<= 1) {
            int y = __shfl_up(xx, off, 16);
            if (lane >= off) xx += y;
        }
        wexc[lane] = xx - s;
    }
    __syncthreads();
    if (tid < nb) bsum[tid] = x - v + wexc[wv];
}

__global__ __launch_bounds__(1024) void block_scan_kernel(const int* __restrict__ cnt,
                                                          const int* __restrict__ bsum,
                                                          int* __restrict__ rowptr,
                                                          int* __restrict__ woff, int n) {
    __shared__ int wsum[16], wexc[16];
    int tid = threadIdx.x, lane = tid & 63, wv = tid >> 6;
    int i = blockIdx.x * 1024 + tid;
    int v = (i < n) ? cnt[i] : 0;
    int x = v;
#pragma unroll
    for (int off = 1; off < 64; off <<= 1) {
        int y = __shfl_up(x, off, 64);
        if (lane >= off) x += y;
    }
    if (lane == 63) wsum[wv] = x;
    __syncthreads();
    if (wv == 0 && lane < 16) {
        int s = wsum[lane];
        int xx = s;
#pragma unroll
        for (int off = 1; off < 16; off <<= 1) {
            int y = __shfl_up(xx, off, 16);
            if (lane >= off) xx += y;
        }
        wexc[lane] = xx - s;
    }
    __syncthreads();
    int excl = x - v + wexc[wv] + bsum[blockIdx.x];
    if (i < n) { rowptr[i] = excl; woff[i] = excl; }
    if (i == n - 1) rowptr[n] = excl + v;
}

__global__ void scatter3_kernel(const int* __restrict__ ei_pp, const int* __restrict__ ei_pw,
                                const int* __restrict__ ei_wp, int* __restrict__ woff,
                                int* __restrict__ perm) {
    int e = blockIdx.x * blockDim.x + threadIdx.x;
    if (e >= ETOT) return;
    const int* ei; int eo, no, E;
    if (e < E_PP) { ei = ei_pp; eo = 0; no = 0; E = E_PP; }
    else if (e < E_PP + E_PW) { ei = ei_pw; eo = E_PP; no = N_P; E = E_PW; }
    else { ei = ei_wp; eo = E_PP + E_PW; no = N_P + N_W; E = E_WP; }
    int el = e - eo;
    int p = atomicAdd(&woff[no + ei[E + el]], 1);
    perm[p] = ei[el];   // type-local src index
}

// ---------------------------------------------------------------------------
// Per-edge unnormalized exp + per-dst inverse-sum. One THREAD per (type,dst).
// ---------------------------------------------------------------------------
__global__ void gat_stats3(const int* __restrict__ rowptr, const int* __restrict__ perm,
                           const float4* __restrict__ a_pp_s, const float4* __restrict__ a_pp_d,
                           const float4* __restrict__ a_pw_s, const float4* __restrict__ a_pw_d,
                           const float4* __restrict__ a_wp_s, const float4* __restrict__ a_wp_d,
                           float4* __restrict__ alpha, float4* __restrict__ inv) {
    int g = blockIdx.x * blockDim.x + threadIdx.x;
    if (g >= NTOT) return;
    const float4 *as, *ad; int d;
    if (g < N_P) { as = a_pp_s; ad = a_pp_d; d = g; }
    else if (g < N_P + N_W) { as = a_pw_s; ad = a_pw_d; d = g - N_P; }
    else { as = a_wp_s; ad = a_wp_d; d = g - (N_P + N_W); }
    int base = rowptr[g], end = rowptr[g + 1];
    float4 adv = ad[d];
    float4 sm = make_float4(0.f, 0.f, 0.f, 0.f);
    for (int i = base; i < end; ++i) {
        float4 asv = as[perm[i]];
        float4 t;
        t.x = __expf(lrelu02(asv.x + adv.x));
        t.y = __expf(lrelu02(asv.y + adv.y));
        t.z = __expf(lrelu02(asv.z + adv.z));
        t.w = __expf(lrelu02(asv.w + adv.w));
        alpha[i] = t;
        sm.x += t.x; sm.y += t.y; sm.z += t.z; sm.w += t.w;
    }
    float4 iv;
    int len = end - base;
    iv.x = len ? 1.f / sm.x : 0.f;
    iv.y = len ? 1.f / sm.y : 0.f;
    iv.z = len ? 1.f / sm.z : 0.f;
    iv.w = len ? 1.f / sm.w : 0.f;
    inv[g] = iv;
}

// Final projections for both node types in one launch.
__global__ void post_out(const float* __restrict__ h_p, const float* __restrict__ h_w,
                         const float* __restrict__ Wp, const float* __restrict__ bpv,
                         const float* __restrict__ Ww, const float* __restrict__ bwv,
                         float* __restrict__ out) {
    int n = blockIdx.x * blockDim.x + threadIdx.x;
    if (n >= N_P + N_W) return;
    const float *h, *W, *bb; float* o;
    if (n < N_P) { h = h_p + (size_t)n * HID; W = Wp; bb = bpv; o = out + (size_t)n * OUTD; }
    else { int m = n - N_P; h = h_w + (size_t)m * HID; W = Ww; bb = bwv; o = out + (size_t)N_P * OUTD + (size_t)m * OUTD; }
    const float4* h4 = (const float4*)h;
    float acc[OUTD];
#pragma unroll
    for (int c = 0; c < OUTD; ++c) acc[c] = bb[c];
#pragma unroll
    for (int k4 = 0; k4 < HID / 4; ++k4) {
        float4 hv = h4[k4];
#pragma unroll
        for (int c = 0; c < OUTD; ++c) {
            acc[c] = fmaf(hv.x, W[(k4 * 4 + 0) * OUTD + c], acc[c]);
            acc[c] = fmaf(hv.y, W[(k4 * 4 + 1) * OUTD + c], acc[c]);
            acc[c] = fmaf(hv.z, W[(k4 * 4 + 2) * OUTD + c], acc[c]);
            acc[c] = fmaf(hv.w, W[(k4 * 4 + 3) * OUTD + c], acc[c]);
        }
    }
#pragma unroll
    for (int c4 = 0; c4 < OUTD / 4; ++c4)
        *(float4*)&o[c4 * 4] = make_float4(acc[c4 * 4], acc[c4 * 4 + 1], acc[c4 * 4 + 2], acc[c4 * 4 + 3]);
}

extern "C" void kernel_launch(void* const* d_in, const int* in_sizes, int n_in,
                              void* d_out, int out_size, void* d_ws, size_t ws_size,
                              hipStream_t stream) {
    const float* x_p    = (const float*)d_in[0];
    const float* x_w    = (const float*)d_in[1];
    const float* Wpp    = (const float*)d_in[2];
    const float* bpp    = (const float*)d_in[3];
    const float* Wpw    = (const float*)d_in[4];
    const float* bpw    = (const float*)d_in[5];
    const float* Wsrc   = (const float*)d_in[6];
    const float* Wdst   = (const float*)d_in[7];
    const float* Asrc   = (const float*)d_in[8];
    const float* Adst   = (const float*)d_in[9];
    const float* cbias  = (const float*)d_in[10];
    const float* Wpostp = (const float*)d_in[11];
    const float* bpostp = (const float*)d_in[12];
    const float* Wpostw = (const float*)d_in[13];
    const float* bpostw = (const float*)d_in[14];
    const int*   ei_pp  = (const int*)d_in[15];
    const int*   ei_pw  = (const int*)d_in[16];
    const int*   ei_wp  = (const int*)d_in[17];

    char* base = (char*)d_ws;
    size_t off = 0;
    auto alloc = [&](size_t bytes) -> void* {
        void* p = base + off;
        off = (off + bytes + 15) & ~(size_t)15;
        return p;
    };

    float*  hp[2];  hp[0]  = (float*)alloc((size_t)N_P * HID * 4);
                    hp[1]  = (float*)alloc((size_t)N_P * HID * 4);
    float*  hw[2];  hw[0]  = (float*)alloc((size_t)N_W * HID * 4);
                    hw[1]  = (float*)alloc((size_t)N_W * HID * 4);
    __half* hp16[2]; hp16[0] = (__half*)alloc((size_t)N_P * HID * 2);
                     hp16[1] = (__half*)alloc((size_t)N_P * HID * 2);
    __half* hw16[2]; hw16[0] = (__half*)alloc((size_t)N_W * HID * 2);
                     hw16[1] = (__half*)alloc((size_t)N_W * HID * 2);
    __half* agg_p  = (__half*)alloc((size_t)N_P * 512 * 2);
    __half* agg_w  = (__half*)alloc((size_t)N_W * 256 * 2);
    float*  wv_s   = (float*)alloc((size_t)LL * 3 * HID * KH * 4);
    float*  wv_d   = (float*)alloc((size_t)LL * 3 * HID * KH * 4);
    __half* wtP    = (__half*)alloc(64 * 256 * 2);
    __half* wtW    = (__half*)alloc(64 * 128 * 2);
    __half* wtp    = (__half*)alloc((size_t)LL * 64 * 512 * 2);
    __half* wtw    = (__half*)alloc((size_t)LL * 64 * 256 * 2);
    float*  bp     = (float*)alloc(LL * 64 * 4);
    float*  bw     = (float*)alloc(LL * 64 * 4);
    float*  a_pp_s = (float*)alloc((size_t)N_P * KH * 4);
    float*  a_pp_d = (float*)alloc((size_t)N_P * KH * 4);
    float*  a_pw_s = (float*)alloc((size_t)N_P * KH * 4);
    float*  a_pw_d = (float*)alloc((size_t)N_W * KH * 4);
    float*  a_wp_s = (float*)alloc((size_t)N_W * KH * 4);
    float*  a_wp_d = (float*)alloc((size_t)N_P * KH * 4);
    float*  alpha  = (float*)alloc((size_t)ETOT * KH * 4);
    float*  inv    = (float*)alloc((size_t)NTOT * KH * 4);
    int*    cnt    = (int*)alloc((size_t)NTOT * 4);
    int*    woff   = (int*)alloc((size_t)NTOT * 4);
    int*    rowptr = (int*)alloc(((size_t)NTOT + 1) * 4);
    int*    perm   = (int*)alloc((size_t)ETOT * 4);
    int*    bsum   = (int*)alloc(1024 * 4);

    auto cdiv = [](long long a, long long b) { return (int)((a + b - 1) / b); };

    // weight preprocessing
    wv_kernel<<<LL * 3, 256, 0, stream>>>(Wsrc, Asrc, wv_s);
    wv_kernel<<<LL * 3, 256, 0, stream>>>(Wdst, Adst, wv_d);
    build_wt_proj<<<cdiv(64 * 256 + 64 * 128, 256), 256, 0, stream>>>(Wpp, Wpw, wtP, wtW);
    build_wcomb16<<<cdiv(LL * 64 * (512 + 256), 256), 256, 0, stream>>>(Wsrc, cbias, wtp, bp, wtw, bw);

    // concatenated CSR build (round-11 proven version)
    int nb = cdiv(NTOT, 1024);
    (void)hipMemsetAsync(cnt, 0, (size_t)NTOT * 4, stream);
    count3_kernel<<<cdiv(ETOT, 256), 256, 0, stream>>>(ei_pp, ei_pw, ei_wp, cnt);
    block_sum_kernel<<<nb, 1024, 0, stream>>>(cnt, bsum, NTOT);
    scan_bsums_kernel<<<1, 1024, 0, stream>>>(bsum, nb);
    block_scan_kernel<<<nb, 1024, 0, stream>>>(cnt, bsum, rowptr, woff, NTOT);
    scatter3_kernel<<<cdiv(ETOT, 256), 256, 0, stream>>>(ei_pp, ei_pw, ei_wp, woff, perm);

    // input projections (both node types, one dispatch)
    mfma_proj2<<<NBP + NBW, 256, 0, stream>>>(x_p, x_w, wtP, wtW, bpp, bpw,
                                              hp[0], hp16[0], hw[0], hw16[0]);

    int cur = 0;
    for (int l = 0; l < LL; ++l) {
        int lt0 = l * 3 + 0, lt1 = l * 3 + 1, lt2 = l * 3 + 2;
        av_multi<4><<<cdiv(N_P, 256), 256, 0, stream>>>(
            hp[cur], wv_s + (size_t)lt0 * 256, wv_d + (size_t)lt0 * 256,
            wv_s + (size_t)lt1 * 256, wv_d + (size_t)lt2 * 256,
            (float4*)a_pp_s, (float4*)a_pp_d, (float4*)a_pw_s, (float4*)a_wp_d, N_P);
        av_multi<2><<<cdiv(N_W, 256), 256, 0, stream>>>(
            hw[cur], wv_d + (size_t)lt1 * 256, wv_s + (size_t)lt2 * 256, nullptr, nullptr,
            (float4*)a_pw_d, (float4*)a_wp_s, nullptr, nullptr, N_W);

        gat_stats3<<<cdiv(NTOT, 256), 256, 0, stream>>>(
            rowptr, perm,
            (const float4*)a_pp_s, (const float4*)a_pp_d,
            (const float4*)a_pw_s, (const float4*)a_pw_d,
            (const float4*)a_wp_s, (const float4*)a_wp_d,
            (float4*)alpha, (float4*)inv);

        gat_msg_all<<<cdiv(N_P + N_W, 4), 256, 0, stream>>>(
            rowptr, perm, (const float4*)alpha, (const float4*)inv,
            hp16[cur], hw16[cur], agg_p, agg_w);

        mfma_postagg2<<<NBP + NBW, 256, 0, stream>>>(
            agg_p, agg_w, wtp + (size_t)l * 64 * 512, wtw + (size_t)l * 64 * 256,
            bp + l * 64, bw + l * 64,
            hp[cur ^ 1], hp16[cur ^ 1], hw[cur ^ 1], hw16[cur ^ 1]);
        cur ^= 1;
    }

    post_out<<<cdiv(N_P + N_W, 256), 256, 0, stream>>>(
        hp[cur], hw[cur], Wpostp, bpostp, Wpostw, bpostw, (float*)d_out);
}

// Round 14
// 359.971 us; speedup vs baseline: 3.2250x; 1.0367x over previous
//
#include <hip/hip_runtime.h>
#include <hip/hip_fp16.h>
#include <cfloat>
#include <cmath>

#define N_P 50000
#define N_W 10000
#define D_P 256
#define D_W 128
#define HID 64
#define OUTD 8
#define KH 4
#define LL 2
#define E_PP 500000
#define E_PW 150000
#define E_WP 150000
#define NTOT (N_P + N_W + N_P)
#define ETOT (E_PP + E_PW + E_WP)
#define NBP ((N_P + 63) / 64)
#define NBW ((N_W + 63) / 64)

typedef _Float16 f16x8 __attribute__((ext_vector_type(8)));
typedef float f32x4 __attribute__((ext_vector_type(4)));

__device__ inline float lrelu02(float v) { return v > 0.f ? v : 0.2f * v; }

__device__ inline f16x8 ld8h(const _Float16* p) { return *(const f16x8*)p; }
__device__ inline f16x8 ld8h(const __half* p) { return *(const f16x8*)p; }
__device__ inline f16x8 ld8h(const float* p) {
    float4 lo = *(const float4*)p;
    float4 hi = *(const float4*)(p + 4);
    f16x8 a = { (_Float16)lo.x, (_Float16)lo.y, (_Float16)lo.z, (_Float16)lo.w,
                (_Float16)hi.x, (_Float16)hi.y, (_Float16)hi.z, (_Float16)hi.w };
    return a;
}

// ---------------------------------------------------------------------------
// Shared MFMA GEMM core: C[M,64] = A[M,K] @ Bt[64,K]^T + bias (opt ELU).
// ---------------------------------------------------------------------------
template<typename AT, bool ELU>
__device__ inline void gemm64_core(const AT* __restrict__ A, const __half* __restrict__ Bt,
                                   const float* __restrict__ bias,
                                   float* __restrict__ C, __half* __restrict__ C16,
                                   int M, int K, int bid) {
    int lane = threadIdx.x & 63;
    int wv = threadIdx.x >> 6;
    int rbase = bid * 64 + wv * 16;
    int arow = min(rbase + (lane & 15), M - 1);
    int kgrp = (lane >> 4) * 8;
    const AT* Ap = A + (size_t)arow * K + kgrp;
    const _Float16* Bp = (const _Float16*)Bt + kgrp;
    int bcol = lane & 15;

    f32x4 acc0 = {0.f, 0.f, 0.f, 0.f};
    f32x4 acc1 = {0.f, 0.f, 0.f, 0.f};
    f32x4 acc2 = {0.f, 0.f, 0.f, 0.f};
    f32x4 acc3 = {0.f, 0.f, 0.f, 0.f};

#pragma unroll 4
    for (int k0 = 0; k0 < K; k0 += 32) {
        f16x8 a = ld8h(Ap + k0);
        f16x8 b0 = *(const f16x8*)(Bp + (size_t)(0 * 16 + bcol) * K + k0);
        f16x8 b1 = *(const f16x8*)(Bp + (size_t)(1 * 16 + bcol) * K + k0);
        f16x8 b2 = *(const f16x8*)(Bp + (size_t)(2 * 16 + bcol) * K + k0);
        f16x8 b3 = *(const f16x8*)(Bp + (size_t)(3 * 16 + bcol) * K + k0);
        acc0 = __builtin_amdgcn_mfma_f32_16x16x32_f16(a, b0, acc0, 0, 0, 0);
        acc1 = __builtin_amdgcn_mfma_f32_16x16x32_f16(a, b1, acc1, 0, 0, 0);
        acc2 = __builtin_amdgcn_mfma_f32_16x16x32_f16(a, b2, acc2, 0, 0, 0);
        acc3 = __builtin_amdgcn_mfma_f32_16x16x32_f16(a, b3, acc3, 0, 0, 0);
    }

    int crow = rbase + (lane >> 4) * 4;
    f32x4 accs[4] = {acc0, acc1, acc2, acc3};
#pragma unroll
    for (int t = 0; t < 4; ++t) {
        int col = t * 16 + (lane & 15);
        float bv = bias[col];
#pragma unroll
        for (int r = 0; r < 4; ++r) {
            int rr = crow + r;
            if (rr < M) {
                float v = accs[t][r] + bv;
                if (ELU) v = v > 0.f ? v : expf(v) - 1.f;
                C[(size_t)rr * 64 + col] = v;
                C16[(size_t)rr * 64 + col] = __float2half(v);
            }
        }
    }
}

// Merged input projections (protein blocks then pathway blocks).
__global__ __launch_bounds__(256) void mfma_proj2(
    const float* __restrict__ xp, const float* __restrict__ xw,
    const __half* __restrict__ wtP, const __half* __restrict__ wtW,
    const float* __restrict__ bpp, const float* __restrict__ bpw,
    float* __restrict__ hp, __half* __restrict__ hp16,
    float* __restrict__ hw, __half* __restrict__ hw16) {
    if (blockIdx.x < NBP)
        gemm64_core<float, false>(xp, wtP, bpp, hp, hp16, N_P, D_P, blockIdx.x);
    else
        gemm64_core<float, false>(xw, wtW, bpw, hw, hw16, N_W, D_W, blockIdx.x - NBP);
}

// Merged post-aggregation projections (protein K=512, pathway K=256), ELU.
__global__ __launch_bounds__(256) void mfma_postagg2(
    const __half* __restrict__ aggp, const __half* __restrict__ aggw,
    const __half* __restrict__ wtp, const __half* __restrict__ wtw,
    const float* __restrict__ bp, const float* __restrict__ bw,
    float* __restrict__ hp, __half* __restrict__ hp16,
    float* __restrict__ hw, __half* __restrict__ hw16) {
    if (blockIdx.x < NBP)
        gemm64_core<__half, true>(aggp, wtp, bp, hp, hp16, N_P, 512, blockIdx.x);
    else
        gemm64_core<__half, true>(aggw, wtw, bw, hw, hw16, N_W, 256, blockIdx.x - NBP);
}

// ---------------------------------------------------------------------------
// Fused aggregation helper: staging lane computes unnormalized alpha from
// attention dots in-register (exp(lrelu(a_s[src]+a_d[dst]))), accumulates a
// per-lane partial denominator; fma loop identical to the proven agg_range.
// ---------------------------------------------------------------------------
__device__ inline void agg_range_f(int base, int len, const int* __restrict__ perm,
                                   const float4* __restrict__ as4, float4 adv,
                                   const __half* __restrict__ h16,
                                   int lane, int wv,
                                   float4 (*s_al)[64], int (*s_sr)[64],
                                   float& a0, float& a1, float& a2, float& a3,
                                   float4& sm) {
    for (int c0 = 0; c0 < len; c0 += 64) {
        int i = c0 + lane;
        if (i < len) {
            int s = perm[base + i];
            float4 asv = as4[s];
            float4 t;
            t.x = __expf(lrelu02(asv.x + adv.x));
            t.y = __expf(lrelu02(asv.y + adv.y));
            t.z = __expf(lrelu02(asv.z + adv.z));
            t.w = __expf(lrelu02(asv.w + adv.w));
            s_sr[wv][lane] = s;
            s_al[wv][lane] = t;
            sm.x += t.x; sm.y += t.y; sm.z += t.z; sm.w += t.w;
        }
        int cnt = min(64, len - c0);
        int j = 0;
        for (; j + 4 <= cnt; j += 4) {
            int sj0 = s_sr[wv][j], sj1 = s_sr[wv][j + 1];
            int sj2 = s_sr[wv][j + 2], sj3 = s_sr[wv][j + 3];
            float h0 = __half2float(h16[(size_t)sj0 * HID + lane]);
            float h1 = __half2float(h16[(size_t)sj1 * HID + lane]);
            float h2 = __half2float(h16[(size_t)sj2 * HID + lane]);
            float h3 = __half2float(h16[(size_t)sj3 * HID + lane]);
            float4 l0 = s_al[wv][j], l1 = s_al[wv][j + 1];
            float4 l2 = s_al[wv][j + 2], l3 = s_al[wv][j + 3];
            a0 = fmaf(l0.x, h0, a0); a1 = fmaf(l0.y, h0, a1);
            a2 = fmaf(l0.z, h0, a2); a3 = fmaf(l0.w, h0, a3);
            a0 = fmaf(l1.x, h1, a0); a1 = fmaf(l1.y, h1, a1);
            a2 = fmaf(l1.z, h1, a2); a3 = fmaf(l1.w, h1, a3);
            a0 = fmaf(l2.x, h2, a0); a1 = fmaf(l2.y, h2, a1);
            a2 = fmaf(l2.z, h2, a2); a3 = fmaf(l2.w, h2, a3);
            a0 = fmaf(l3.x, h3, a0); a1 = fmaf(l3.y, h3, a1);
            a2 = fmaf(l3.z, h3, a2); a3 = fmaf(l3.w, h3, a3);
        }
        for (; j < cnt; ++j) {
            int sj = s_sr[wv][j];
            float4 al = s_al[wv][j];
            float hv = __half2float(h16[(size_t)sj * HID + lane]);
            a0 = fmaf(al.x, hv, a0); a1 = fmaf(al.y, hv, a1);
            a2 = fmaf(al.z, hv, a2); a3 = fmaf(al.w, hv, a3);
        }
    }
}

__device__ inline float4 wave_sum4(float4 v) {
#pragma unroll
    for (int off = 32; off > 0; off >>= 1) {
        v.x += __shfl_xor(v.x, off, 64);
        v.y += __shfl_xor(v.y, off, 64);
        v.z += __shfl_xor(v.z, off, 64);
        v.w += __shfl_xor(v.w, off, 64);
    }
    return v;
}

// ---------------------------------------------------------------------------
// One dispatch for ALL message aggregation, softmax fused in.
// Slots: [0,N_P) protein (pp+wp ranges), [N_P,N_P+N_W) pathway (pw range).
// ---------------------------------------------------------------------------
__global__ __launch_bounds__(256) void gat_msg_fused(
    const int* __restrict__ rowptr, const int* __restrict__ perm,
    const float4* __restrict__ a_pp_s, const float4* __restrict__ a_pp_d,
    const float4* __restrict__ a_pw_s, const float4* __restrict__ a_pw_d,
    const float4* __restrict__ a_wp_s, const float4* __restrict__ a_wp_d,
    const __half* __restrict__ hp16, const __half* __restrict__ hw16,
    __half* __restrict__ agg_p, __half* __restrict__ agg_w) {
    __shared__ float4 s_al[4][64];
    __shared__ int s_sr[4][64];
    int lane = threadIdx.x & 63;
    int wv = threadIdx.x >> 6;
    int d = (blockIdx.x << 2) + wv;
    if (d >= N_P + N_W) return;

    if (d < N_P) {
        float a0 = 0.f, a1 = 0.f, a2 = 0.f, a3 = 0.f;
        float b0 = 0.f, b1 = 0.f, b2 = 0.f, b3 = 0.f;
        float4 sm1 = make_float4(0.f, 0.f, 0.f, 0.f);
        float4 sm2 = make_float4(0.f, 0.f, 0.f, 0.f);
        int g1 = d, g2 = N_P + N_W + d;
        int base1 = rowptr[g1], len1 = rowptr[g1 + 1] - base1;
        int base2 = rowptr[g2], len2 = rowptr[g2 + 1] - base2;
        agg_range_f(base1, len1, perm, a_pp_s, a_pp_d[d], hp16, lane, wv,
                    s_al, s_sr, a0, a1, a2, a3, sm1);
        agg_range_f(base2, len2, perm, a_wp_s, a_wp_d[d], hw16, lane, wv,
                    s_al, s_sr, b0, b1, b2, b3, sm2);
        sm1 = wave_sum4(sm1);
        sm2 = wave_sum4(sm2);
        float4 i1, i2;
        i1.x = len1 ? 1.f / sm1.x : 0.f;
        i1.y = len1 ? 1.f / sm1.y : 0.f;
        i1.z = len1 ? 1.f / sm1.z : 0.f;
        i1.w = len1 ? 1.f / sm1.w : 0.f;
        i2.x = len2 ? 1.f / sm2.x : 0.f;
        i2.y = len2 ? 1.f / sm2.y : 0.f;
        i2.z = len2 ? 1.f / sm2.z : 0.f;
        i2.w = len2 ? 1.f / sm2.w : 0.f;
        size_t ob = (size_t)d * 512 + lane;
        agg_p[ob]       = __float2half(a0 * i1.x);
        agg_p[ob + 64]  = __float2half(a1 * i1.y);
        agg_p[ob + 128] = __float2half(a2 * i1.z);
        agg_p[ob + 192] = __float2half(a3 * i1.w);
        agg_p[ob + 256] = __float2half(b0 * i2.x);
        agg_p[ob + 320] = __float2half(b1 * i2.y);
        agg_p[ob + 384] = __float2half(b2 * i2.z);
        agg_p[ob + 448] = __float2half(b3 * i2.w);
    } else {
        int d2 = d - N_P;
        int g = N_P + d2;
        float a0 = 0.f, a1 = 0.f, a2 = 0.f, a3 = 0.f;
        float4 sm = make_float4(0.f, 0.f, 0.f, 0.f);
        int base = rowptr[g], len = rowptr[g + 1] - base;
        agg_range_f(base, len, perm, a_pw_s, a_pw_d[d2], hp16, lane, wv,
                    s_al, s_sr, a0, a1, a2, a3, sm);
        sm = wave_sum4(sm);
        float4 iv;
        iv.x = len ? 1.f / sm.x : 0.f;
        iv.y = len ? 1.f / sm.y : 0.f;
        iv.z = len ? 1.f / sm.z : 0.f;
        iv.w = len ? 1.f / sm.w : 0.f;
        size_t ob = (size_t)d2 * 256 + lane;
        agg_w[ob]       = __float2half(a0 * iv.x);
        agg_w[ob + 64]  = __float2half(a1 * iv.y);
        agg_w[ob + 128] = __float2half(a2 * iv.z);
        agg_w[ob + 192] = __float2half(a3 * iv.w);
    }
}

// Fused multi-target attention dots: oJ[n] = h[n,0:64] @ WJ[64,4]. NJ jobs.
template<int NJ>
__global__ void av_multi(const float* __restrict__ h,
                         const float* __restrict__ W0, const float* __restrict__ W1,
                         const float* __restrict__ W2, const float* __restrict__ W3,
                         float4* __restrict__ o0, float4* __restrict__ o1,
                         float4* __restrict__ o2, float4* __restrict__ o3, int M) {
    int n = blockIdx.x * blockDim.x + threadIdx.x;
    if (n >= M) return;
    const float4* h4 = (const float4*)(h + (size_t)n * HID);
    float a0[4] = {0.f, 0.f, 0.f, 0.f}, a1[4] = {0.f, 0.f, 0.f, 0.f};
    float a2[4] = {0.f, 0.f, 0.f, 0.f}, a3[4] = {0.f, 0.f, 0.f, 0.f};
#pragma unroll
    for (int k4 = 0; k4 < 16; ++k4) {
        float4 hv = h4[k4];
        float hvv[4] = {hv.x, hv.y, hv.z, hv.w};
#pragma unroll
        for (int r = 0; r < 4; ++r) {
            int f = k4 * 4 + r;
            float x = hvv[r];
#pragma unroll
            for (int c = 0; c < 4; ++c) a0[c] = fmaf(x, W0[f * 4 + c], a0[c]);
#pragma unroll
            for (int c = 0; c < 4; ++c) a1[c] = fmaf(x, W1[f * 4 + c], a1[c]);
            if (NJ > 2) {
#pragma unroll
                for (int c = 0; c < 4; ++c) a2[c] = fmaf(x, W2[f * 4 + c], a2[c]);
#pragma unroll
                for (int c = 0; c < 4; ++c) a3[c] = fmaf(x, W3[f * 4 + c], a3[c]);
            }
        }
    }
    o0[n] = make_float4(a0[0], a0[1], a0[2], a0[3]);
    o1[n] = make_float4(a1[0], a1[1], a1[2], a1[3]);
    if (NJ > 2) {
        o2[n] = make_float4(a2[0], a2[1], a2[2], a2[3]);
        o3[n] = make_float4(a3[0], a3[1], a3[2], a3[3]);
    }
}

// wv[lt][j,k] = sum_h W[lt][j, k*64+h] * att[lt][k,h].
__global__ void wv_kernel(const float* __restrict__ W, const float* __restrict__ att,
                          float* __restrict__ wv) {
    int lt = blockIdx.x;
    int j = threadIdx.x >> 2, k = threadIdx.x & 3;
    const float* Wp = W + (size_t)lt * HID * (KH * HID) + (size_t)j * (KH * HID) + k * HID;
    const float* ap = att + (size_t)lt * KH * HID + k * HID;
    float s = 0.f;
    for (int h = 0; h < HID; ++h) s += Wp[h] * ap[h];
    wv[(size_t)lt * HID * KH + j * KH + k] = s;
}

// Transposed fp16 proj weights: wtP[c][k] = Wpp[k][c] (64x256), wtW (64x128).
__global__ void build_wt_proj(const float* __restrict__ Wpp, const float* __restrict__ Wpw,
                              __half* __restrict__ wtP, __half* __restrict__ wtW) {
    int t = blockIdx.x * blockDim.x + threadIdx.x;
    if (t < 64 * 256) {
        int c = t >> 8, k = t & 255;
        wtP[t] = __float2half(Wpp[k * 64 + c]);
    } else if (t < 64 * 256 + 64 * 128) {
        int u = t - 64 * 256;
        int c = u >> 7, k = u & 127;
        wtW[u] = __float2half(Wpw[k * 64 + c]);
    }
}

// Transposed fp16 combined weights for BOTH layers; head-mean (0.25) and
// hetero-mean (0.5) folded here ONLY (alpha normalization lives in msg).
__global__ void build_wcomb16(const float* __restrict__ Wsrc, const float* __restrict__ cbias,
                              __half* __restrict__ wtp, float* __restrict__ bp,
                              __half* __restrict__ wtw, float* __restrict__ bw) {
    int t = blockIdx.x * blockDim.x + threadIdx.x;
    const int P = LL * 64 * 512;
    if (t < P) {
        int l = t / (64 * 512);
        int rem = t % (64 * 512);
        int h = rem >> 9, r = rem & 511;
        int part = r >> 8, k = (r & 255) >> 6, j = r & 63;
        int type = (part == 0) ? 0 : 2;
        wtp[t] = __float2half(Wsrc[(((size_t)l * 3 + type) * 64 + j) * 256 + k * 64 + h] * 0.125f);
    } else if (t < P + LL * 64 * 256) {
        int u = t - P;
        int l = u / (64 * 256);
        int rem = u % (64 * 256);
        int h = rem >> 8, r = rem & 255;
        int k = r >> 6, j = r & 63;
        wtw[u] = __float2half(Wsrc[(((size_t)l * 3 + 1) * 64 + j) * 256 + k * 64 + h] * 0.25f);
    }
    if (t < LL * 64) {
        int l = t >> 6, c = t & 63;
        bp[t] = 0.5f * (cbias[(l * 3 + 0) * 64 + c] + cbias[(l * 3 + 2) * 64 + c]);
        bw[t] = cbias[(l * 3 + 1) * 64 + c];
    }
}

// ---------------- concatenated CSR build (round-11 proven version) ----------
__global__ void count3_kernel(const int* __restrict__ ei_pp, const int* __restrict__ ei_pw,
                              const int* __restrict__ ei_wp, int* __restrict__ cnt) {
    int e = blockIdx.x * blockDim.x + threadIdx.x;
    if (e >= ETOT) return;
    const int* ei; int eo, no, E;
    if (e < E_PP) { ei = ei_pp; eo = 0; no = 0; E = E_PP; }
    else if (e < E_PP + E_PW) { ei = ei_pw; eo = E_PP; no = N_P; E = E_PW; }
    else { ei = ei_wp; eo = E_PP + E_PW; no = N_P + N_W; E = E_WP; }
    int el = e - eo;
    atomicAdd(&cnt[no + ei[E + el]], 1);
}

__global__ __launch_bounds__(1024) void block_sum_kernel(const int* __restrict__ cnt,
                                                         int* __restrict__ bsum, int n) {
    __shared__ int wsum[16];
    int tid = threadIdx.x, lane = tid & 63, wv = tid >> 6;
    int i = blockIdx.x * 1024 + tid;
    int v = (i < n) ? cnt[i] : 0;
#pragma unroll
    for (int off = 32; off > 0; off >>= 1) v += __shfl_xor(v, off, 64);
    if (lane == 0) wsum[wv] = v;
    __syncthreads();
    if (tid == 0) {
        int t = 0;
#pragma unroll
        for (int k = 0; k < 16; ++k) t += wsum[k];
        bsum[blockIdx.x] = t;
    }
}

__global__ __launch_bounds__(1024) void scan_bsums_kernel(int* __restrict__ bsum, int nb) {
    __shared__ int wsum[16], wexc[16];
    int tid = threadIdx.x, lane = tid & 63, wv = tid >> 6;
    int v = (tid < nb) ? bsum[tid] : 0;
    int x = v;
#pragma unroll
    for (int off = 1; off < 64; off <<= 1) {
        int y = __shfl_up(x, off, 64);
        if (lane >= off) x += y;
    }
    if (lane == 63) wsum[wv] = x;
    __syncthreads();
    if (wv == 0 && lane < 16) {
        int s = wsum[lane];
        int xx = s;
#pragma unroll
        for (int off = 1; off < 16; off <<= 1) {
            int y = __shfl_up(xx, off, 16);
            if (lane >= off) xx += y;
        }
        wexc[lane] = xx - s;
    }
    __syncthreads();
    if (tid < nb) bsum[tid] = x - v + wexc[wv];
}

__global__ __launch_bounds__(1024) void block_scan_kernel(const int* __restrict__ cnt,
                                                          const int* __restrict__ bsum,
                                                          int* __restrict__ rowptr,
                                                          int* __restrict__ woff, int n) {
    __shared__ int wsum[16], wexc[16];
    int tid = threadIdx.x, lane = tid & 63, wv = tid >> 6;
    int i = blockIdx.x * 1024 + tid;
    int v = (i < n) ? cnt[i] : 0;
    int x = v;
#pragma unroll
    for (int off = 1; off < 64; off <<= 1) {
        int y = __shfl_up(x, off, 64);
        if (lane >= off) x += y;
    }
    if (lane == 63) wsum[wv] = x;
    __syncthreads();
    if (wv == 0 && lane < 16) {
        int s = wsum[lane];
        int xx = s;
#pragma unroll
        for (int off = 1; off < 16; off <<= 1) {
            int y = __shfl_up(xx, off, 16);
            if (lane >= off) xx += y;
        }
        wexc[lane] = xx - s;
    }
    __syncthreads();
    int excl = x - v + wexc[wv] + bsum[blockIdx.x];
    if (i < n) { rowptr[i] = excl; woff[i] = excl; }
    if (i == n - 1) rowptr[n] = excl + v;
}

__global__ void scatter3_kernel(const int* __restrict__ ei_pp, const int* __restrict__ ei_pw,
                                const int* __restrict__ ei_wp, int* __restrict__ woff,
                                int* __restrict__ perm) {
    int e = blockIdx.x * blockDim.x + threadIdx.x;
    if (e >= ETOT) return;
    const int* ei; int eo, no, E;
    if (e < E_PP) { ei = ei_pp; eo = 0; no = 0; E = E_PP; }
    else if (e < E_PP + E_PW) { ei = ei_pw; eo = E_PP; no = N_P; E = E_PW; }
    else { ei = ei_wp; eo = E_PP + E_PW; no = N_P + N_W; E = E_WP; }
    int el = e - eo;
    int p = atomicAdd(&woff[no + ei[E + el]], 1);
    perm[p] = ei[el];   // type-local src index
}

// Final projections for both node types in one launch.
__global__ void post_out(const float* __restrict__ h_p, const float* __restrict__ h_w,
                         const float* __restrict__ Wp, const float* __restrict__ bpv,
                         const float* __restrict__ Ww, const float* __restrict__ bwv,
                         float* __restrict__ out) {
    int n = blockIdx.x * blockDim.x + threadIdx.x;
    if (n >= N_P + N_W) return;
    const float *h, *W, *bb; float* o;
    if (n < N_P) { h = h_p + (size_t)n * HID; W = Wp; bb = bpv; o = out + (size_t)n * OUTD; }
    else { int m = n - N_P; h = h_w + (size_t)m * HID; W = Ww; bb = bwv; o = out + (size_t)N_P * OUTD + (size_t)m * OUTD; }
    const float4* h4 = (const float4*)h;
    float acc[OUTD];
#pragma unroll
    for (int c = 0; c < OUTD; ++c) acc[c] = bb[c];
#pragma unroll
    for (int k4 = 0; k4 < HID / 4; ++k4) {
        float4 hv = h4[k4];
#pragma unroll
        for (int c = 0; c < OUTD; ++c) {
            acc[c] = fmaf(hv.x, W[(k4 * 4 + 0) * OUTD + c], acc[c]);
            acc[c] = fmaf(hv.y, W[(k4 * 4 + 1) * OUTD + c], acc[c]);
            acc[c] = fmaf(hv.z, W[(k4 * 4 + 2) * OUTD + c], acc[c]);
            acc[c] = fmaf(hv.w, W[(k4 * 4 + 3) * OUTD + c], acc[c]);
        }
    }
#pragma unroll
    for (int c4 = 0; c4 < OUTD / 4; ++c4)
        *(float4*)&o[c4 * 4] = make_float4(acc[c4 * 4], acc[c4 * 4 + 1], acc[c4 * 4 + 2], acc[c4 * 4 + 3]);
}

extern "C" void kernel_launch(void* const* d_in, const int* in_sizes, int n_in,
                              void* d_out, int out_size, void* d_ws, size_t ws_size,
                              hipStream_t stream) {
    const float* x_p    = (const float*)d_in[0];
    const float* x_w    = (const float*)d_in[1];
    const float* Wpp    = (const float*)d_in[2];
    const float* bpp    = (const float*)d_in[3];
    const float* Wpw    = (const float*)d_in[4];
    const float* bpw    = (const float*)d_in[5];
    const float* Wsrc   = (const float*)d_in[6];
    const float* Wdst   = (const float*)d_in[7];
    const float* Asrc   = (const float*)d_in[8];
    const float* Adst   = (const float*)d_in[9];
    const float* cbias  = (const float*)d_in[10];
    const float* Wpostp = (const float*)d_in[11];
    const float* bpostp = (const float*)d_in[12];
    const float* Wpostw = (const float*)d_in[13];
    const float* bpostw = (const float*)d_in[14];
    const int*   ei_pp  = (const int*)d_in[15];
    const int*   ei_pw  = (const int*)d_in[16];
    const int*   ei_wp  = (const int*)d_in[17];

    char* base = (char*)d_ws;
    size_t off = 0;
    auto alloc = [&](size_t bytes) -> void* {
        void* p = base + off;
        off = (off + bytes + 15) & ~(size_t)15;
        return p;
    };

    float*  hp[2];  hp[0]  = (float*)alloc((size_t)N_P * HID * 4);
                    hp[1]  = (float*)alloc((size_t)N_P * HID * 4);
    float*  hw[2];  hw[0]  = (float*)alloc((size_t)N_W * HID * 4);
                    hw[1]  = (float*)alloc((size_t)N_W * HID * 4);
    __half* hp16[2]; hp16[0] = (__half*)alloc((size_t)N_P * HID * 2);
                     hp16[1] = (__half*)alloc((size_t)N_P * HID * 2);
    __half* hw16[2]; hw16[0] = (__half*)alloc((size_t)N_W * HID * 2);
                     hw16[1] = (__half*)alloc((size_t)N_W * HID * 2);
    __half* agg_p  = (__half*)alloc((size_t)N_P * 512 * 2);
    __half* agg_w  = (__half*)alloc((size_t)N_W * 256 * 2);
    float*  wv_s   = (float*)alloc((size_t)LL * 3 * HID * KH * 4);
    float*  wv_d   = (float*)alloc((size_t)LL * 3 * HID * KH * 4);
    __half* wtP    = (__half*)alloc(64 * 256 * 2);
    __half* wtW    = (__half*)alloc(64 * 128 * 2);
    __half* wtp    = (__half*)alloc((size_t)LL * 64 * 512 * 2);
    __half* wtw    = (__half*)alloc((size_t)LL * 64 * 256 * 2);
    float*  bp     = (float*)alloc(LL * 64 * 4);
    float*  bw     = (float*)alloc(LL * 64 * 4);
    float*  a_pp_s = (float*)alloc((size_t)N_P * KH * 4);
    float*  a_pp_d = (float*)alloc((size_t)N_P * KH * 4);
    float*  a_pw_s = (float*)alloc((size_t)N_P * KH * 4);
    float*  a_pw_d = (float*)alloc((size_t)N_W * KH * 4);
    float*  a_wp_s = (float*)alloc((size_t)N_W * KH * 4);
    float*  a_wp_d = (float*)alloc((size_t)N_P * KH * 4);
    int*    cnt    = (int*)alloc((size_t)NTOT * 4);
    int*    woff   = (int*)alloc((size_t)NTOT * 4);
    int*    rowptr = (int*)alloc(((size_t)NTOT + 1) * 4);
    int*    perm   = (int*)alloc((size_t)ETOT * 4);
    int*    bsum   = (int*)alloc(1024 * 4);

    auto cdiv = [](long long a, long long b) { return (int)((a + b - 1) / b); };

    // weight preprocessing
    wv_kernel<<<LL * 3, 256, 0, stream>>>(Wsrc, Asrc, wv_s);
    wv_kernel<<<LL * 3, 256, 0, stream>>>(Wdst, Adst, wv_d);
    build_wt_proj<<<cdiv(64 * 256 + 64 * 128, 256), 256, 0, stream>>>(Wpp, Wpw, wtP, wtW);
    build_wcomb16<<<cdiv(LL * 64 * (512 + 256), 256), 256, 0, stream>>>(Wsrc, cbias, wtp, bp, wtw, bw);

    // concatenated CSR build (round-11 proven version)
    int nb = cdiv(NTOT, 1024);
    (void)hipMemsetAsync(cnt, 0, (size_t)NTOT * 4, stream);
    count3_kernel<<<cdiv(ETOT, 256), 256, 0, stream>>>(ei_pp, ei_pw, ei_wp, cnt);
    block_sum_kernel<<<nb, 1024, 0, stream>>>(cnt, bsum, NTOT);
    scan_bsums_kernel<<<1, 1024, 0, stream>>>(bsum, nb);
    block_scan_kernel<<<nb, 1024, 0, stream>>>(cnt, bsum, rowptr, woff, NTOT);
    scatter3_kernel<<<cdiv(ETOT, 256), 256, 0, stream>>>(ei_pp, ei_pw, ei_wp, woff, perm);

    // input projections (both node types, one dispatch)
    mfma_proj2<<<NBP + NBW, 256, 0, stream>>>(x_p, x_w, wtP, wtW, bpp, bpw,
                                              hp[0], hp16[0], hw[0], hw16[0]);

    int cur = 0;
    for (int l = 0; l < LL; ++l) {
        int lt0 = l * 3 + 0, lt1 = l * 3 + 1, lt2 = l * 3 + 2;
        av_multi<4><<<cdiv(N_P, 256), 256, 0, stream>>>(
            hp[cur], wv_s + (size_t)lt0 * 256, wv_d + (size_t)lt0 * 256,
            wv_s + (size_t)lt1 * 256, wv_d + (size_t)lt2 * 256,
            (float4*)a_pp_s, (float4*)a_pp_d, (float4*)a_pw_s, (float4*)a_wp_d, N_P);
        av_multi<2><<<cdiv(N_W, 256), 256, 0, stream>>>(
            hw[cur], wv_d + (size_t)lt1 * 256, wv_s + (size_t)lt2 * 256, nullptr, nullptr,
            (float4*)a_pw_d, (float4*)a_wp_s, nullptr, nullptr, N_W);

        gat_msg_fused<<<cdiv(N_P + N_W, 4), 256, 0, stream>>>(
            rowptr, perm,
            (const float4*)a_pp_s, (const float4*)a_pp_d,
            (const float4*)a_pw_s, (const float4*)a_pw_d,
            (const float4*)a_wp_s, (const float4*)a_wp_d,
            hp16[cur], hw16[cur], agg_p, agg_w);

        mfma_postagg2<<<NBP + NBW, 256, 0, stream>>>(
            agg_p, agg_w, wtp + (size_t)l * 64 * 512, wtw + (size_t)l * 64 * 256,
            bp + l * 64, bw + l * 64,
            hp[cur ^ 1], hp16[cur ^ 1], hw[cur ^ 1], hw16[cur ^ 1]);
        cur ^= 1;
    }

    post_out<<<cdiv(N_P + N_W, 256), 256, 0, stream>>>(
        hp[cur], hw[cur], Wpostp, bpostp, Wpostw, bpostw, (float*)d_out);
}